// Round 7
// baseline (179.957 us; speedup 1.0000x reference)
//
#include <hip/hip_runtime.h>

#define BB 8
#define NS 5
#define NQ 75
#define NG 4
#define NF 49
#define CDIM 64

#define SUP2 8192                       // packed support rows: BB*NG*256 (245 real + 11 pad per (b,g))
#define QB   8192                       // first query row in ws
#define QRYR (BB * NQ * NG * 64)        // 153600 query rows
#define TOT2 (SUP2 + QRYR)              // 161792 rows x 64 bf16
#define NFORM (BB * NS)                 // 40 forms blocks (loop g inside)
#define NCROSS (BB * NQ * NG * 2)       // 4800
#define NQQ (BB * NQ * NG)              // 2400

typedef __attribute__((ext_vector_type(8))) short bf16x8;
typedef __attribute__((ext_vector_type(16))) float f32x16;

__device__ __forceinline__ float multi_gauss(float d2) {
    d2 = fmaxf(d2, 0.f);
    float e  = __expf(-0.125f * d2);
    float e2 = e * e, e4 = e2 * e2, e8 = e4 * e4, e16 = e8 * e8;
    return e + e2 + e4 + e8 + e16;
}
// arg = -0.125*log2(e)*d2 (<=0)
__device__ __forceinline__ float multi_gauss2(float arg) {
    float e  = __builtin_amdgcn_exp2f(fminf(arg, 0.f));
    float e2 = e * e, e4 = e2 * e2, e8 = e4 * e4, e16 = e8 * e8;
    return ((e + e2) + (e4 + e8)) + e16;
}
__device__ __forceinline__ unsigned short f2bf(float x) {
    union { float f; unsigned u; } c; c.f = x;
    unsigned r = c.u + 0x7FFFu + ((c.u >> 16) & 1u);
    return (unsigned short)(r >> 16);
}
__device__ __forceinline__ float bf2f(unsigned short h) {
    union { float f; unsigned u; } c; c.u = ((unsigned)h) << 16; return c.f;
}
__device__ __forceinline__ float wred(float x) {
    for (int o = 32; o; o >>= 1) x += __shfl_down(x, o, 64);
    return x;
}

// ---------------------------------------------------------------------------
// Kernel 1: prep. Blocks [0,40): ss quadratic forms per (b,s), loop over g,
// STORE 0.25*beta^T Kss beta into out (overwrites poison; no zeroing pass).
// Blocks [40,...): streaming fp32->bf16 (packed support + query) + row ssq.
// ---------------------------------------------------------------------------
__global__ __launch_bounds__(256) void prep(
    const float* __restrict__ sup, const float* __restrict__ qry,
    const float* __restrict__ beta,
    unsigned short* __restrict__ whi, float* __restrict__ wssq,
    float* __restrict__ out)
{
    __shared__ __align__(16) unsigned short A[64 * 72];   // Sh (bf16 support) then Kt (bf16 K)
    __shared__ __align__(16) unsigned short Bt[96 * 72];  // bf16 beta^T [v][i]
    __shared__ float fssq[64];
    __shared__ float red_s[96];

    int blk = blockIdx.x;
    int t = threadIdx.x;
    int w = t >> 6, lane = t & 63, lrow = lane & 31, lhalf = lane >> 5;

    if (blk >= NFORM) {
        // ---------------- streaming convert ----------------
        int idx = (blk - NFORM) * 256 + t;
        int row = idx >> 4, c4 = idx & 15;
        const float* src = nullptr;
        if (row < SUP2) {
            int bg = row >> 8, p = row & 255;
            int b = bg >> 2, g = bg & 3;
            int s = p / 49, i = p - s * 49;
            if (p < 245) src = sup + ((size_t)(((b * NS + s) * NG + g) * NF + i)) * CDIM + c4 * 4;
        } else {
            int r2 = row - SUP2;
            int t6 = r2 >> 6, j = r2 & 63;
            int g = t6 & 3, v = (t6 >> 2) % NQ, b = t6 / (NQ * NG);
            if (j < NF) src = qry + ((size_t)(((b * NQ + v) * NG + g) * NF + j)) * CDIM + c4 * 4;
        }
        float4 x = make_float4(0.f, 0.f, 0.f, 0.f);
        if (src) x = *(const float4*)src;
        ushort4 h4;
        h4.x = f2bf(x.x); h4.y = f2bf(x.y); h4.z = f2bf(x.z); h4.w = f2bf(x.w);
        ((ushort4*)whi)[idx] = h4;
        float v2 = x.x * x.x + x.y * x.y + x.z * x.z + x.w * x.w;
        v2 += __shfl_down(v2, 8, 64);
        v2 += __shfl_down(v2, 4, 64);
        v2 += __shfl_down(v2, 2, 64);
        v2 += __shfl_down(v2, 1, 64);
        if ((idx & 15) == 0) wssq[row] = v2;
        return;
    }

    // ---------------- ss forms: one block per (b,s), loop g ----------------
    int b = blk / NS, s = blk % NS;
    if (t < 96) red_s[t] = 0.f;

    for (int g = 0; g < NG; ++g) {
        __syncthreads();   // previous g's reads of A/Bt done; red_s init visible
        // stage support tile (fp32 -> bf16) + row ssq
        for (int u = t; u < 1024; u += 256) {
            int i = u >> 4, c4 = u & 15;
            float4 x = make_float4(0.f, 0.f, 0.f, 0.f);
            if (i < NF)
                x = *(const float4*)(sup + ((size_t)(((b * NS + s) * NG + g) * NF + i)) * CDIM + c4 * 4);
            ushort4 h4;
            h4.x = f2bf(x.x); h4.y = f2bf(x.y); h4.z = f2bf(x.z); h4.w = f2bf(x.w);
            *(ushort4*)&A[i * 72 + c4 * 4] = h4;
            float v2 = x.x * x.x + x.y * x.y + x.z * x.z + x.w * x.w;
            v2 += __shfl_down(v2, 8, 64);
            v2 += __shfl_down(v2, 4, 64);
            v2 += __shfl_down(v2, 2, 64);
            v2 += __shfl_down(v2, 1, 64);
            if ((u & 15) == 0) fssq[i] = v2;
        }
        // stage beta^T bf16 (96 x 64, zero-padded)
        for (int u = t; u < 96 * 64; u += 256) {
            int v = u >> 6, j = u & 63;
            unsigned short val = 0;
            if (v < NQ && j < NF)
                val = f2bf(beta[(size_t)(((b * NQ + v) * NS + s) * NG + g) * NF + j]);
            Bt[v * 72 + j] = val;
        }
        __syncthreads();

        // K = Kss 64x64 via MFMA (wave tile mt,nt)
        int mt = w >> 1, nt = w & 1;
        f32x16 acc;
#pragma unroll
        for (int q = 0; q < 16; ++q) acc[q] = 0.f;
#pragma unroll
        for (int kc = 0; kc < 4; ++kc) {
            int ko = kc * 2 + lhalf;
            bf16x8 a  = *(const bf16x8*)&A[(mt * 32 + lrow) * 72 + ko * 8];
            bf16x8 bb = *(const bf16x8*)&A[(nt * 32 + lrow) * 72 + ko * 8];
            acc = __builtin_amdgcn_mfma_f32_32x32x16_bf16(a, bb, acc, 0, 0, 0);
        }
        __syncthreads();   // all Sh reads done; A reusable as Kt

        int cj = nt * 32 + lrow;
        float sqj = fssq[cj];
#pragma unroll
        for (int reg = 0; reg < 16; ++reg) {
            int ri = mt * 32 + (reg & 3) + 8 * (reg >> 2) + 4 * lhalf;
            float kv = (ri == cj) ? 5.0f : multi_gauss(fssq[ri] + sqj - 2.f * acc[reg]);
            A[ri * 72 + cj] = f2bf(kv);
        }
        __syncthreads();   // Kt complete

        // Y = K . Bt^T (6 tiles over 4 waves, 2 passes), dot with beta
#pragma unroll
        for (int pass = 0; pass < 2; ++pass) {
            int T = (pass == 0) ? w : ((w < 2) ? 4 + w : -1);
            if (T < 0) continue;
            int m = T & 1, n = T >> 1;
            f32x16 yacc;
#pragma unroll
            for (int q = 0; q < 16; ++q) yacc[q] = 0.f;
#pragma unroll
            for (int kc = 0; kc < 4; ++kc) {
                int ko = kc * 2 + lhalf;
                bf16x8 af = *(const bf16x8*)&A[(m * 32 + lrow) * 72 + ko * 8];
                bf16x8 bf = *(const bf16x8*)&Bt[(n * 32 + lrow) * 72 + ko * 8];
                yacc = __builtin_amdgcn_mfma_f32_32x32x16_bf16(af, bf, yacc, 0, 0, 0);
            }
            int vcol = n * 32 + lrow;
            float p = 0.f;
#pragma unroll
            for (int reg = 0; reg < 16; ++reg) {
                int i = m * 32 + (reg & 3) + 8 * (reg >> 2) + 4 * lhalf;
                p = fmaf(yacc[reg], bf2f(Bt[vcol * 72 + i]), p);
            }
            p += __shfl_xor(p, 32, 64);
            if (lane < 32) atomicAdd(&red_s[vcol], p);
        }
    }
    __syncthreads();
    if (t < NQ)
        out[((size_t)b * NQ + t) * NS + s] = 0.25f * red_s[t];   // STORE (covers poison)
}

// ---------------------------------------------------------------------------
// Kernel 2: main. Blocks [0,4800): cross per (b,v,g,half) — 8 packed m-tiles,
// 2 acc/wave. Blocks [4800,7200): qq per (b,v,g) — 4 tiles, 1 acc/wave.
// Both atomicAdd into out.
// ---------------------------------------------------------------------------
__global__ __launch_bounds__(256, 6) void mmd_main(
    const unsigned short* __restrict__ whi, const float* __restrict__ wssq,
    const float* __restrict__ beta, const float* __restrict__ gamma,
    float* __restrict__ out)
{
    __shared__ __align__(16) union {
        struct { float ssqS[256]; float sbetaF[256]; float red_sq[NS]; } c;
        struct { float sgam[NS][64]; float ssqQ[64]; float red_qq[NS]; } q;
    } sm;

    int blk = blockIdx.x;
    int t = threadIdx.x;
    int w = t >> 6, lane = t & 63, lrow = lane & 31, lhalf = lane >> 5;
    const bf16x8* W = (const bf16x8*)whi;
    const float c2  = -0.18033688f;   // -0.125 * log2(e)
    const float k2c =  0.36067376f;   // -2 * c2

    if (blk < NCROSS) {
        // ===================== cross path =====================
        int h = blk & 1;
        int g = (blk >> 1) & 3;
        int v = (blk >> 3) % NQ;
        int b = blk / (NQ * NG * 2);
        int qc = h * 32;

        int srow0 = (b * NG + g) * 256;
        int qrow0 = QB + ((b * NQ + v) * NG + g) * 64;

        {   // stage packed ssq + packed beta
            int p = t;
            sm.c.ssqS[p] = wssq[srow0 + p];
            int s = p / 49, i = p - s * 49;
            sm.c.sbetaF[p] = (p < 245)
                ? beta[(size_t)(((b * NQ + v) * NS + s) * NG + g) * NF + i] : 0.f;
            if (t < NS) sm.c.red_sq[t] = 0.f;
        }
        int qcol = qc + lrow;
        float qsq = wssq[qrow0 + qcol];
        float gamv[NS];
#pragma unroll
        for (int s = 0; s < NS; ++s)
            gamv[s] = (qcol < NF)
                ? gamma[(size_t)(((b * NQ + v) * NS + s) * NG + g) * NF + qcol] : 0.f;

        f32x16 acc[2];
#pragma unroll
        for (int mi = 0; mi < 2; ++mi)
#pragma unroll
            for (int q = 0; q < 16; ++q) acc[mi][q] = 0.f;
#pragma unroll
        for (int kc = 0; kc < 4; ++kc) {
            int ko = kc * 2 + lhalf;
            bf16x8 bh = W[(qrow0 + qcol) * 8 + ko];
            bf16x8 a0 = W[(srow0 + w * 32 + lrow) * 8 + ko];
            bf16x8 a1 = W[(srow0 + (w + 4) * 32 + lrow) * 8 + ko];
            acc[0] = __builtin_amdgcn_mfma_f32_32x32x16_bf16(a0, bh, acc[0], 0, 0, 0);
            acc[1] = __builtin_amdgcn_mfma_f32_32x32x16_bf16(a1, bh, acc[1], 0, 0, 0);
        }
        __syncthreads();

        float c2q = c2 * qsq;
#pragma unroll
        for (int mi = 0; mi < 2; ++mi) {
            int mt = w + 4 * mi;
            int s_lo = (mt * 32) / 49;
            int bnd = (s_lo + 1) * 49;
            int s_hi = (s_lo < 4) ? s_lo + 1 : 4;
            float tA = 0.f, tB = 0.f;
#pragma unroll
            for (int grp = 0; grp < 4; ++grp) {
                int rbase = mt * 32 + grp * 8 + 4 * lhalf;
                float4 sqv = *(const float4*)&sm.c.ssqS[rbase];
                float4 bvv = *(const float4*)&sm.c.sbetaF[rbase];
#pragma unroll
                for (int q = 0; q < 4; ++q) {
                    float sq = (q == 0) ? sqv.x : (q == 1) ? sqv.y : (q == 2) ? sqv.z : sqv.w;
                    float bv = (q == 0) ? bvv.x : (q == 1) ? bvv.y : (q == 2) ? bvv.z : bvv.w;
                    float arg = fmaf(k2c, acc[mi][grp * 4 + q], fmaf(c2, sq, c2q));
                    float con = bv * multi_gauss2(arg);
                    bool lo = (rbase + q) < bnd;
                    tA += lo ? con : 0.f;
                    tB += lo ? 0.f : con;
                }
            }
            tA *= gamv[s_lo];
            tB *= gamv[s_hi];
            tA = wred(tA);
            tB = wred(tB);
            if (lane == 0) {
                atomicAdd(&sm.c.red_sq[s_lo], tA);
                atomicAdd(&sm.c.red_sq[s_hi], tB);
            }
        }
        __syncthreads();
        if (t < NS)
            atomicAdd(&out[((size_t)b * NQ + v) * NS + t], -0.5f * sm.c.red_sq[t]);
    } else {
        // ===================== qq path =====================
        int k = blk - NCROSS;
        int g = k & 3;
        int v = (k >> 2) % NQ;
        int b = k / (NQ * NG);
        int qrow0 = QB + ((b * NQ + v) * NG + g) * 64;

        for (int u = t; u < NS * 64; u += 256) {
            int s = u >> 6, i = u & 63;
            sm.q.sgam[s][i] = (i < NF)
                ? gamma[(size_t)(((b * NQ + v) * NS + s) * NG + g) * NF + i] : 0.f;
        }
        if (t < 64) sm.q.ssqQ[t] = wssq[qrow0 + t];
        if (t < NS) sm.q.red_qq[t] = 0.f;

        int mt = w >> 1, nt = w & 1;
        f32x16 acc;
#pragma unroll
        for (int q = 0; q < 16; ++q) acc[q] = 0.f;
#pragma unroll
        for (int kc = 0; kc < 4; ++kc) {
            int ko = kc * 2 + lhalf;
            bf16x8 a  = W[(qrow0 + mt * 32 + lrow) * 8 + ko];
            bf16x8 bb = W[(qrow0 + nt * 32 + lrow) * 8 + ko];
            acc = __builtin_amdgcn_mfma_f32_32x32x16_bf16(a, bb, acc, 0, 0, 0);
        }
        __syncthreads();

        int col = nt * 32 + lrow;
        float csq = sm.q.ssqQ[col];
        float c2q = c2 * csq;
        float gcol[NS];
#pragma unroll
        for (int s = 0; s < NS; ++s) gcol[s] = sm.q.sgam[s][col];

        float qs[NS] = {0.f, 0.f, 0.f, 0.f, 0.f};
#pragma unroll
        for (int grp = 0; grp < 4; ++grp) {
            int rbase = mt * 32 + grp * 8 + 4 * lhalf;
            float4 sqv = *(const float4*)&sm.q.ssqQ[rbase];
            float kvv[4];
#pragma unroll
            for (int q = 0; q < 4; ++q) {
                float sq = (q == 0) ? sqv.x : (q == 1) ? sqv.y : (q == 2) ? sqv.z : sqv.w;
                int row = rbase + q;
                float arg = fmaf(k2c, acc[grp * 4 + q], fmaf(c2, sq, c2q));
                kvv[q] = (row == col) ? 5.0f : multi_gauss2(arg);
            }
#pragma unroll
            for (int s = 0; s < NS; ++s) {
                float4 gi = *(const float4*)&sm.q.sgam[s][rbase];
                qs[s] = fmaf(gi.x, kvv[0], qs[s]);
                qs[s] = fmaf(gi.y, kvv[1], qs[s]);
                qs[s] = fmaf(gi.z, kvv[2], qs[s]);
                qs[s] = fmaf(gi.w, kvv[3], qs[s]);
            }
        }
#pragma unroll
        for (int s = 0; s < NS; ++s) {
            float r = wred(qs[s] * gcol[s]);
            if (lane == 0) atomicAdd(&sm.q.red_qq[s], r);
        }
        __syncthreads();
        if (t < NS)
            atomicAdd(&out[((size_t)b * NQ + v) * NS + t], 0.25f * sm.q.red_qq[t]);
    }
}

extern "C" void kernel_launch(void* const* d_in, const int* in_sizes, int n_in,
                              void* d_out, int out_size, void* d_ws, size_t ws_size,
                              hipStream_t stream) {
    const float* sup   = (const float*)d_in[0];
    const float* qry   = (const float*)d_in[1];
    const float* beta  = (const float*)d_in[2];
    const float* gamma = (const float*)d_in[3];
    float* out = (float*)d_out;

    unsigned short* whi = (unsigned short*)d_ws;                 // TOT2*64 bf16 = 20.7 MB
    float* wssq = (float*)(whi + (size_t)TOT2 * 64);             // TOT2 floats

    prep<<<NFORM + (TOT2 * 16) / 256, 256, 0, stream>>>(sup, qry, beta, whi, wssq, out);
    mmd_main<<<NCROSS + NQQ, 256, 0, stream>>>(whi, wssq, beta, gamma, out);
}